// Round 1
// baseline (419.296 us; speedup 1.0000x reference)
//
#include <hip/hip_runtime.h>
#include <math.h>

#define N_PTS   16384
#define F_DIM   64
#define K_BINS  32
#define C_DIM   128
#define FK      2048     // F*K
#define YPS     132      // Y' row stride: [y0..y127, ysq, 1, 0, 0]
#define WPS     132      // W row stride:  [w0..w127, S1, B, pad, pad]
#define EPS_F   1e-8f

// ---------------------------------------------------------------------------
// Kernel 0: Y' = [teacher (128) | y_sq | 1 | 0 | 0], one 32-lane group per row
// ---------------------------------------------------------------------------
__global__ __launch_bounds__(256) void build_yp_k(const float* __restrict__ y,
                                                  float* __restrict__ yp) {
    const int t    = threadIdx.x;
    const int r    = blockIdx.x * 8 + (t >> 5);
    const int lane = t & 31;
    const float4 v = reinterpret_cast<const float4*>(y + (size_t)r * C_DIM)[lane];
    float sq = v.x * v.x + v.y * v.y + v.z * v.z + v.w * v.w;
#pragma unroll
    for (int m = 16; m >= 1; m >>= 1) sq += __shfl_xor(sq, m, 64);  // within 32-group
    float* row = yp + (size_t)r * YPS;
    reinterpret_cast<float4*>(row)[lane] = v;
    if (lane == 0) {
        row[128] = sq; row[129] = 1.0f; row[130] = 0.0f; row[131] = 0.0f;
    }
}

// ---------------------------------------------------------------------------
// Kernel 1: split-K GEMM  W_part[ch][fk][c] = sum_{n in chunk} M[n][fk]*Y'[n][c]
// Block: 256 threads, fk-tile = 64 (2 features), all 128 c, per-thread 4k x 8c.
// Extra columns (S1 = M^T y_sq, B = column sums) via per-thread side duty.
// ---------------------------------------------------------------------------
__global__ __launch_bounds__(256) void gemm_mty_k(const float* __restrict__ M,
                                                  const float* __restrict__ yp,
                                                  float* __restrict__ wpart,
                                                  int cn) {
    __shared__ __align__(16) float m_s[8][64];
    __shared__ __align__(16) float y_s[8][YPS];
    __shared__ float pB[8][64];
    __shared__ float pS[8][64];

    const int t   = threadIdx.x;
    const int bf  = blockIdx.x;        // 0..31 -> fk tile of 64
    const int ch  = blockIdx.y;        // split-K chunk
    const int fk0 = bf * 64;
    const int n0  = ch * cn;
    const int tc  = t & 15;            // c = tc*4+j  and  64+tc*4+j  (2-way LDS alias: free)
    const int tk  = t >> 4;            // k = tk*4+i
    const int rnu = t >> 5;            // 0..7  (B/S1 duty row)
    const int rkk = t & 31;

    float accA[4][4] = {};
    float accB4[4][4] = {};
    float bAcc0 = 0.f, bAcc1 = 0.f, sAcc0 = 0.f, sAcc1 = 0.f;

    for (int nb = 0; nb < cn; nb += 8) {
        // stage M tile (8 x 64), coalesced 256B rows
        {
            const int nu = t >> 6, kk = t & 63;
            m_s[nu][kk]     = M[(size_t)(n0 + nb + nu) * FK + fk0 + kk];
            m_s[nu + 4][kk] = M[(size_t)(n0 + nb + nu + 4) * FK + fk0 + kk];
        }
        // stage Y' tile (8 x 132) = 264 float4
        {
            int q = t;
            int nu = q / 33, c4 = q % 33;
            reinterpret_cast<float4*>(y_s[nu])[c4] =
                reinterpret_cast<const float4*>(yp + (size_t)(n0 + nb + nu) * YPS)[c4];
            if (t < 8) {
                q = t + 256; nu = q / 33; c4 = q % 33;
                reinterpret_cast<float4*>(y_s[nu])[c4] =
                    reinterpret_cast<const float4*>(yp + (size_t)(n0 + nb + nu) * YPS)[c4];
            }
        }
        __syncthreads();
#pragma unroll
        for (int nu = 0; nu < 8; ++nu) {
            const float4 mv4 = *reinterpret_cast<const float4*>(&m_s[nu][tk * 4]);
            const float4 ya4 = *reinterpret_cast<const float4*>(&y_s[nu][tc * 4]);
            const float4 yb4 = *reinterpret_cast<const float4*>(&y_s[nu][64 + tc * 4]);
            const float mv[4] = {mv4.x, mv4.y, mv4.z, mv4.w};
            const float ya[4] = {ya4.x, ya4.y, ya4.z, ya4.w};
            const float yb[4] = {yb4.x, yb4.y, yb4.z, yb4.w};
#pragma unroll
            for (int i = 0; i < 4; ++i) {
#pragma unroll
                for (int j = 0; j < 4; ++j) {
                    accA[i][j]  = fmaf(mv[i], ya[j], accA[i][j]);
                    accB4[i][j] = fmaf(mv[i], yb[j], accB4[i][j]);
                }
            }
        }
        // B / S1 duty: each thread owns 2 (nu,k) slots of the staged tile
        {
            const float m0 = m_s[rnu][rkk];
            const float m1 = m_s[rnu][32 + rkk];
            const float q  = y_s[rnu][128];
            bAcc0 += m0;               bAcc1 += m1;
            sAcc0 = fmaf(m0, q, sAcc0); sAcc1 = fmaf(m1, q, sAcc1);
        }
        __syncthreads();
    }

    pB[rnu][rkk] = bAcc0; pB[rnu][32 + rkk] = bAcc1;
    pS[rnu][rkk] = sAcc0; pS[rnu][32 + rkk] = sAcc1;
    __syncthreads();

    float* wbase = wpart + (size_t)ch * FK * WPS;
#pragma unroll
    for (int i = 0; i < 4; ++i) {
        float* row = wbase + (size_t)(fk0 + tk * 4 + i) * WPS;
        const float4 a = make_float4(accA[i][0], accA[i][1], accA[i][2], accA[i][3]);
        const float4 b = make_float4(accB4[i][0], accB4[i][1], accB4[i][2], accB4[i][3]);
        reinterpret_cast<float4*>(row)[tc]      = a;   // c = tc*4
        reinterpret_cast<float4*>(row)[16 + tc] = b;   // c = 64 + tc*4
    }
    if (t < 64) {
        float B = 0.f, S = 0.f;
#pragma unroll
        for (int nu = 0; nu < 8; ++nu) { B += pB[nu][t]; S += pS[nu][t]; }
        float* row = wbase + (size_t)(fk0 + t) * WPS;
        row[128] = S; row[129] = B;
    }
}

// ---------------------------------------------------------------------------
// Kernel 2: per-feature epilogue. One block per f.
//   centroids = W/B; wv = (S1 - c_sq*(B+EPS))/B  (exact algebraic identity for
//   the reference's sum_n m*(y_sq + c_sq - 2*cross) / B);  entropy; repulsion;
//   strict-upper Gram for inter. Wl row stride 133 -> conflict-free Gram reads.
// ---------------------------------------------------------------------------
__global__ __launch_bounds__(256) void finalize_k(const float* __restrict__ wpart,
                                                  int nchunk,
                                                  float* __restrict__ fpart) {
    __shared__ float Wl[32][133];
    __shared__ float Bv[32], Binv[32], S1v[32], csq[32];
    __shared__ float scr[32][8];
    __shared__ float4 red4[256];
    const int t = threadIdx.x;
    const int f = blockIdx.x;

    // reduce split-K partials: cols 0..129
    for (int e = t; e < 32 * 130; e += 256) {
        const int k = e / 130, c = e % 130;
        const size_t idx = (size_t)(f * 32 + k) * WPS + c;
        float s = 0.f;
        for (int ch = 0; ch < nchunk; ++ch)
            s += wpart[idx + (size_t)ch * FK * WPS];
        Wl[k][c] = s;
    }
    __syncthreads();
    if (t < 32) {
        const float B = Wl[t][129] + EPS_F;
        Bv[t] = B; Binv[t] = 1.0f / B; S1v[t] = Wl[t][128];
    }
    __syncthreads();
    // centroids in place + c_sq partials
    {
        const int k = t >> 3, g = t & 7;
        const float ib = Binv[k];
        float s = 0.f;
        for (int c = g * 16; c < g * 16 + 16; ++c) {
            const float v = Wl[k][c] * ib;
            Wl[k][c] = v;
            s = fmaf(v, v, s);
        }
        scr[k][g] = s;
    }
    __syncthreads();
    if (t < 32) {
        float s = 0.f;
#pragma unroll
        for (int g = 0; g < 8; ++g) s += scr[t][g];
        csq[t] = s;
    }
    __syncthreads();

    float my_disp = 0.f, my_ent = 0.f, my_rep = 0.f, my_inter = 0.f;
    if (t < 32) {
        const float B = Bv[t];
        my_disp = (S1v[t] - csq[t] * (B + EPS_F)) * Binv[t];
        const float p = B * (1.0f / (float)N_PTS);
        my_ent = p * logf(p + EPS_F);
    }
    // neighbor repulsion
    {
        const int pr = t >> 3, g = t & 7;
        float s = 0.f;
        if (pr < 31) {
            for (int c = g * 16; c < g * 16 + 16; ++c) {
                const float d = Wl[pr][c] - Wl[pr + 1][c];
                s = fmaf(d, d, s);
            }
        }
        __syncthreads();   // csq consumed scr above; safe to overwrite now
        scr[pr][g] = s;
    }
    __syncthreads();
    if (t < 31) {
        float d = 0.f;
#pragma unroll
        for (int g = 0; g < 8; ++g) d += scr[t][g];
        my_rep = expf(-d);
    }
    // all-pairs inter (strict upper): 1024 slots over 4 passes
#pragma unroll
    for (int s4 = 0; s4 < 4; ++s4) {
        const int slot = t + s4 * 256;
        const int k = slot >> 5, j = slot & 31;
        if (k < j) {
            float dot = 0.f;
            for (int c = 0; c < 128; ++c) dot = fmaf(Wl[k][c], Wl[j][c], dot);
            const float d = csq[k] + csq[j] - 2.0f * dot;
            my_inter += expf(-d);
        }
    }
    red4[t] = make_float4(my_disp, my_ent, my_rep, my_inter);
    __syncthreads();
    for (int off = 128; off >= 1; off >>= 1) {
        if (t < off) {
            const float4 a = red4[t], b = red4[t + off];
            red4[t] = make_float4(a.x + b.x, a.y + b.y, a.z + b.z, a.w + b.w);
        }
        __syncthreads();
    }
    if (t == 0) {
        fpart[f * 4 + 0] = red4[0].x;
        fpart[f * 4 + 1] = red4[0].y;
        fpart[f * 4 + 2] = red4[0].z;
        fpart[f * 4 + 3] = red4[0].w;
    }
}

// ---------------------------------------------------------------------------
// Kernel 3: reduce 64 per-feature partials -> 5 scalar outputs
// ---------------------------------------------------------------------------
__global__ void final_reduce_k(const float* __restrict__ fpart,
                               float* __restrict__ out) {
    const int t = threadIdx.x;  // 64 threads
    float4 v = reinterpret_cast<const float4*>(fpart)[t];
#pragma unroll
    for (int m = 32; m >= 1; m >>= 1) {
        v.x += __shfl_xor(v.x, m, 64);
        v.y += __shfl_xor(v.y, m, 64);
        v.z += __shfl_xor(v.z, m, 64);
        v.w += __shfl_xor(v.w, m, 64);
    }
    if (t == 0) {
        const float disp  = v.x, ent = v.y, rep = v.z;
        const float inter = v.w * (1.0f / (float)F_DIM);
        out[0] = disp + 0.1f * ent + 0.5f * rep + 0.3f * inter;  // total
        out[1] = disp;
        out[2] = ent;
        out[3] = rep;
        out[4] = inter;
    }
}

extern "C" void kernel_launch(void* const* d_in, const int* in_sizes, int n_in,
                              void* d_out, int out_size, void* d_ws, size_t ws_size,
                              hipStream_t stream) {
    const float* M = (const float*)d_in[0];   // (16384, 64, 32)
    const float* Y = (const float*)d_in[1];   // (16384, 128)
    float* out = (float*)d_out;               // 5 floats
    char*  ws  = (char*)d_ws;

    const size_t yp_bytes = (size_t)N_PTS * YPS * sizeof(float);   // 8.65 MB
    float* yp    = (float*)ws;
    float* fpart = (float*)(ws + yp_bytes);                        // 64*4 floats
    float* wpart = (float*)(ws + yp_bytes + 1024);

    const size_t per_chunk = (size_t)FK * WPS * sizeof(float);     // 1.08 MB
    const size_t avail = (ws_size > yp_bytes + 1024) ? (ws_size - yp_bytes - 1024) : 0;
    int nchunk = 32;                                               // split-K factor
    while (nchunk > 1 && (size_t)nchunk * per_chunk > avail) nchunk >>= 1;
    const int cn = N_PTS / nchunk;                                 // multiple of 8

    build_yp_k<<<dim3(N_PTS / 8), dim3(256), 0, stream>>>(Y, yp);
    gemm_mty_k<<<dim3(32, nchunk), dim3(256), 0, stream>>>(M, yp, wpart, cn);
    finalize_k<<<dim3(F_DIM), dim3(256), 0, stream>>>(wpart, nchunk, fpart);
    final_reduce_k<<<dim3(1), dim3(64), 0, stream>>>(fpart, out);
}

// Round 2
// 270.170 us; speedup vs baseline: 1.5520x; 1.5520x over previous
//
#include <hip/hip_runtime.h>
#include <math.h>

#define N_PTS   16384
#define F_DIM   64
#define K_BINS  32
#define C_DIM   128
#define FK      2048      // F*K
#define CP      144       // padded c-rows in Yt: [y0..y127, ysq, 1, zeros...]
#define CW      132       // W row stride: [w0..w127, S1, B, pad0, pad0]
#define EPS_F   1e-8f

typedef _Float16 f16x8 __attribute__((ext_vector_type(8)));
typedef float    f32x4 __attribute__((ext_vector_type(4)));

static __device__ inline unsigned pack_h2(float a, float b) {
    union { _Float16 h[2]; unsigned u; } x;
    x.h[0] = (_Float16)a; x.h[1] = (_Float16)b;
    return x.u;
}

// ---------------------------------------------------------------------------
// K0: build Yt[c][n] fp16, c-rows: 0..127 = Y^T, 128 = y_sq, 129 = 1.0,
//     130..143 = 0. One block per 64 n.
// ---------------------------------------------------------------------------
__global__ __launch_bounds__(256) void build_yt_k(const float* __restrict__ Y,
                                                  _Float16* __restrict__ Yt) {
    __shared__ __align__(16) float Yl[64][132];
    __shared__ float ysql[64];
    const int t  = threadIdx.x;
    const int n0 = blockIdx.x * 64;
    const int nl = t >> 5;        // 0..7
    const int c4 = t & 31;
#pragma unroll
    for (int p = 0; p < 8; ++p) {
        const int n = p * 8 + nl;
        const float4 v = reinterpret_cast<const float4*>(Y + (size_t)(n0 + n) * C_DIM)[c4];
        reinterpret_cast<float4*>(Yl[n])[c4] = v;
        float sq = v.x * v.x + v.y * v.y + v.z * v.z + v.w * v.w;
#pragma unroll
        for (int m = 16; m >= 1; m >>= 1) sq += __shfl_xor(sq, m, 64);
        if (c4 == 0) ysql[n] = sq;
    }
    __syncthreads();
    unsigned* YtU = (unsigned*)Yt;              // row stride N/2 dwords
    const int nd0 = n0 >> 1;
    const int n2  = t & 31;
    const int rr  = t >> 5;
#pragma unroll
    for (int p = 0; p < 16; ++p) {
        const int c = p * 8 + rr;
        YtU[(size_t)c * (N_PTS / 2) + nd0 + n2] = pack_h2(Yl[2 * n2][c], Yl[2 * n2 + 1][c]);
    }
    if (t < 32) {
        YtU[(size_t)128 * (N_PTS / 2) + nd0 + t] = pack_h2(ysql[2 * t], ysql[2 * t + 1]);
    } else if (t < 64) {
        YtU[(size_t)129 * (N_PTS / 2) + nd0 + (t - 32)] = 0x3C003C00u;  // (1.0h, 1.0h)
    }
    for (int idx = t; idx < 14 * 32; idx += 256) {
        YtU[(size_t)(130 + (idx >> 5)) * (N_PTS / 2) + nd0 + (idx & 31)] = 0u;
    }
}

// ---------------------------------------------------------------------------
// K1: split-K MFMA GEMM. wpart[ch][fk][c] = sum_{n in chunk} M[n][fk]*Yt[c][n]
// Block: 256 thr, fk-tile 64 (wave w owns fk sub-tile w*16), 9 c-tiles of 16.
// A from LDS-staged fp32 M tile ([32][65]: conflict-light), B direct from
// global Yt (L1/L2 resident, identical across the 4 waves).
// ---------------------------------------------------------------------------
__global__ __launch_bounds__(256) void gemm_k(const float* __restrict__ M,
                                              const _Float16* __restrict__ Yt,
                                              float* __restrict__ wpart,
                                              int cn) {
    __shared__ float M_lds[32][65];
    const int t    = threadIdx.x;
    const int fk0  = blockIdx.x * 64;
    const int ch   = blockIdx.y;
    const int n0   = ch * cn;
    const int w    = t >> 6;
    const int l    = t & 63;
    const int quad = l >> 4;
    const int cl   = l & 15;
    const int fkl  = w * 16 + cl;           // A-frag row (fk) within tile
    const int r2   = t >> 4;                // staging row-pair 0..15
    const int fk4  = (t & 15) * 4;

    f32x4 acc[9] = {};

    const float* Mp = M + (size_t)n0 * FK + fk0 + fk4;
    float4 v0 = *reinterpret_cast<const float4*>(Mp + (size_t)(2 * r2) * FK);
    float4 v1 = *reinterpret_cast<const float4*>(Mp + (size_t)(2 * r2 + 1) * FK);

    for (int nb = 0; nb < cn; nb += 32) {
        __syncthreads();
        M_lds[2 * r2][fk4 + 0] = v0.x; M_lds[2 * r2][fk4 + 1] = v0.y;
        M_lds[2 * r2][fk4 + 2] = v0.z; M_lds[2 * r2][fk4 + 3] = v0.w;
        M_lds[2 * r2 + 1][fk4 + 0] = v1.x; M_lds[2 * r2 + 1][fk4 + 1] = v1.y;
        M_lds[2 * r2 + 1][fk4 + 2] = v1.z; M_lds[2 * r2 + 1][fk4 + 3] = v1.w;
        __syncthreads();
        if (nb + 32 < cn) {   // prefetch next M tile (overlaps B-loads + MFMA)
            const float* Mn = M + (size_t)(n0 + nb + 32) * FK + fk0 + fk4;
            v0 = *reinterpret_cast<const float4*>(Mn + (size_t)(2 * r2) * FK);
            v1 = *reinterpret_cast<const float4*>(Mn + (size_t)(2 * r2 + 1) * FK);
        }
        const size_t nbq = (size_t)(n0 + nb + quad * 8);
        f16x8 b[9];
#pragma unroll
        for (int ct = 0; ct < 9; ++ct)
            b[ct] = *reinterpret_cast<const f16x8*>(Yt + (size_t)(ct * 16 + cl) * N_PTS + nbq);
        f16x8 a;
#pragma unroll
        for (int j = 0; j < 8; ++j)
            a[j] = (_Float16)M_lds[quad * 8 + j][fkl];
#pragma unroll
        for (int ct = 0; ct < 9; ++ct)
            acc[ct] = __builtin_amdgcn_mfma_f32_16x16x32_f16(a, b[ct], acc[ct], 0, 0, 0);
    }

    // D layout: col = lane&15, row = quad*4 + reg
    float* wp = wpart + (size_t)ch * FK * CW;
#pragma unroll
    for (int ct = 0; ct < 9; ++ct) {
        const int c = ct * 16 + cl;
        if (c < CW) {
#pragma unroll
            for (int rr = 0; rr < 4; ++rr) {
                const int fk = fk0 + w * 16 + quad * 4 + rr;
                wp[(size_t)fk * CW + c] = acc[ct][rr];
            }
        }
    }
}

// ---------------------------------------------------------------------------
// R1: coalesced chunk reduction wpart -> W. 264 blocks, independent loads.
// ---------------------------------------------------------------------------
__global__ __launch_bounds__(256) void reduce_w_k(const float* __restrict__ wpart,
                                                  float* __restrict__ W, int nchunk) {
    const int idx = blockIdx.x * 256 + threadIdx.x;   // float4 index, grid exact
    const float4* src = reinterpret_cast<const float4*>(wpart);
    const size_t cs = (size_t)FK * CW / 4;
    float4 s = src[idx];
    for (int ch = 1; ch < nchunk; ++ch) {
        const float4 v = src[idx + (size_t)ch * cs];
        s.x += v.x; s.y += v.y; s.z += v.z; s.w += v.w;
    }
    reinterpret_cast<float4*>(W)[idx] = s;
}

// ---------------------------------------------------------------------------
// R2: per-feature epilogue on reduced W. wv = (S1 - c_sq*(B'+EPS))/B' (exact
// identity), entropy, neighbor repulsion, strict-upper Gram for inter.
// ---------------------------------------------------------------------------
__global__ __launch_bounds__(256) void epilogue_k(const float* __restrict__ W,
                                                  float* __restrict__ fpart) {
    __shared__ __align__(16) float Wl[32][CW];
    __shared__ float Bv[32], Binv[32], S1v[32], csq[32];
    __shared__ float scr[32][8];
    __shared__ float4 red4[256];
    const int t = threadIdx.x;
    const int f = blockIdx.x;

    for (int e = t; e < 32 * 33; e += 256) {
        const int k = e / 33, c4 = e % 33;
        reinterpret_cast<float4*>(Wl[k])[c4] =
            reinterpret_cast<const float4*>(W + (size_t)(f * 32 + k) * CW)[c4];
    }
    __syncthreads();
    if (t < 32) {
        const float B = Wl[t][129] + EPS_F;
        Bv[t] = B; Binv[t] = 1.0f / B; S1v[t] = Wl[t][128];
    }
    __syncthreads();
    {   // centroids in place + c_sq partials
        const int k = t >> 3, g = t & 7;
        const float ib = Binv[k];
        float s = 0.f;
        for (int c = g * 16; c < g * 16 + 16; ++c) {
            const float v = Wl[k][c] * ib;
            Wl[k][c] = v;
            s = fmaf(v, v, s);
        }
        scr[k][g] = s;
    }
    __syncthreads();
    if (t < 32) {
        float s = 0.f;
#pragma unroll
        for (int g = 0; g < 8; ++g) s += scr[t][g];
        csq[t] = s;
    }
    __syncthreads();

    float my_disp = 0.f, my_ent = 0.f, my_rep = 0.f, my_inter = 0.f;
    if (t < 32) {
        my_disp = (S1v[t] - csq[t] * (Bv[t] + EPS_F)) * Binv[t];
        const float p = Bv[t] * (1.0f / (float)N_PTS);
        my_ent = p * logf(p + EPS_F);
    }
    {   // neighbor repulsion
        const int pr = t >> 3, g = t & 7;
        float s = 0.f;
        if (pr < 31) {
            for (int c = g * 16; c < g * 16 + 16; ++c) {
                const float d = Wl[pr][c] - Wl[pr + 1][c];
                s = fmaf(d, d, s);
            }
        }
        __syncthreads();
        scr[pr][g] = s;
    }
    __syncthreads();
    if (t < 31) {
        float d = 0.f;
#pragma unroll
        for (int g = 0; g < 8; ++g) d += scr[t][g];
        my_rep = expf(-d);
    }
    // all-pairs inter (strict upper), float4 dots
#pragma unroll
    for (int s4 = 0; s4 < 4; ++s4) {
        const int slot = t + s4 * 256;
        const int k = slot >> 5, j = slot & 31;
        if (k < j) {
            float dot = 0.f;
            for (int c4 = 0; c4 < 32; ++c4) {
                const float4 a = reinterpret_cast<const float4*>(Wl[k])[c4];
                const float4 b = reinterpret_cast<const float4*>(Wl[j])[c4];
                dot = fmaf(a.x, b.x, dot); dot = fmaf(a.y, b.y, dot);
                dot = fmaf(a.z, b.z, dot); dot = fmaf(a.w, b.w, dot);
            }
            my_inter += expf(-(csq[k] + csq[j] - 2.0f * dot));
        }
    }
    red4[t] = make_float4(my_disp, my_ent, my_rep, my_inter);
    __syncthreads();
    for (int off = 128; off >= 1; off >>= 1) {
        if (t < off) {
            const float4 a = red4[t], b = red4[t + off];
            red4[t] = make_float4(a.x + b.x, a.y + b.y, a.z + b.z, a.w + b.w);
        }
        __syncthreads();
    }
    if (t == 0) {
        fpart[f * 4 + 0] = red4[0].x;
        fpart[f * 4 + 1] = red4[0].y;
        fpart[f * 4 + 2] = red4[0].z;
        fpart[f * 4 + 3] = red4[0].w;
    }
}

// ---------------------------------------------------------------------------
// K3: reduce 64 per-feature partials -> 5 scalar outputs
// ---------------------------------------------------------------------------
__global__ void final_reduce_k(const float* __restrict__ fpart,
                               float* __restrict__ out) {
    const int t = threadIdx.x;  // 64 threads
    float4 v = reinterpret_cast<const float4*>(fpart)[t];
#pragma unroll
    for (int m = 32; m >= 1; m >>= 1) {
        v.x += __shfl_xor(v.x, m, 64);
        v.y += __shfl_xor(v.y, m, 64);
        v.z += __shfl_xor(v.z, m, 64);
        v.w += __shfl_xor(v.w, m, 64);
    }
    if (t == 0) {
        const float disp  = v.x, ent = v.y, rep = v.z;
        const float inter = v.w * (1.0f / (float)F_DIM);
        out[0] = disp + 0.1f * ent + 0.5f * rep + 0.3f * inter;
        out[1] = disp;
        out[2] = ent;
        out[3] = rep;
        out[4] = inter;
    }
}

extern "C" void kernel_launch(void* const* d_in, const int* in_sizes, int n_in,
                              void* d_out, int out_size, void* d_ws, size_t ws_size,
                              hipStream_t stream) {
    const float* M = (const float*)d_in[0];   // (16384, 64, 32) fp32
    const float* Y = (const float*)d_in[1];   // (16384, 128) fp32
    float* out = (float*)d_out;               // 5 floats
    char*  ws  = (char*)d_ws;

    const size_t ytBytes = (size_t)CP * N_PTS * sizeof(_Float16);  // 4,718,592
    const size_t wBytes  = (size_t)FK * CW * sizeof(float);        // 1,081,344

    _Float16* Yt    = (_Float16*)ws;
    float*    W     = (float*)(ws + ytBytes);
    float*    fpart = (float*)(ws + ytBytes + wBytes);
    float*    wpart = (float*)(ws + ytBytes + wBytes + 1024);

    const size_t used = ytBytes + wBytes + 1024;
    int nchunk = 32;    // split-K factor -> 1024 blocks (4/CU)
    while (nchunk > 1 && used + (size_t)nchunk * wBytes > ws_size) nchunk >>= 1;
    const int cn = N_PTS / nchunk;   // multiple of 32

    build_yt_k<<<dim3(N_PTS / 64), dim3(256), 0, stream>>>(Y, Yt);
    gemm_k<<<dim3(32, nchunk), dim3(256), 0, stream>>>(M, Yt, wpart, cn);
    reduce_w_k<<<dim3(FK * CW / 4 / 256), dim3(256), 0, stream>>>(wpart, W, nchunk);
    epilogue_k<<<dim3(F_DIM), dim3(256), 0, stream>>>(W, fpart);
    final_reduce_k<<<dim3(1), dim3(64), 0, stream>>>(fpart, out);
}

// Round 3
// 241.326 us; speedup vs baseline: 1.7375x; 1.1195x over previous
//
#include <hip/hip_runtime.h>
#include <math.h>

#define N_PTS   16384
#define F_DIM   64
#define K_BINS  32
#define C_DIM   128
#define FK      2048      // F*K
#define CP      144       // padded c-rows in Yt: [y0..y127, ysq, 1, zeros...]
#define CW      132       // W row stride: [w0..w127, S1, B, pad0, pad0]
#define EPS_F   1e-8f

typedef _Float16 f16x8 __attribute__((ext_vector_type(8)));
typedef float    f32x4 __attribute__((ext_vector_type(4)));

static __device__ inline unsigned pack_h2(float a, float b) {
    union { _Float16 h[2]; unsigned u; } x;
    x.h[0] = (_Float16)a; x.h[1] = (_Float16)b;
    return x.u;
}

// ---------------------------------------------------------------------------
// K0: build Yt[c][n] fp16, c-rows: 0..127 = Y^T, 128 = y_sq, 129 = 1.0,
//     130..143 = 0. One block per 64 n.
// ---------------------------------------------------------------------------
__global__ __launch_bounds__(256) void build_yt_k(const float* __restrict__ Y,
                                                  _Float16* __restrict__ Yt) {
    __shared__ __align__(16) float Yl[64][132];
    __shared__ float ysql[64];
    const int t  = threadIdx.x;
    const int n0 = blockIdx.x * 64;
    const int nl = t >> 5;        // 0..7
    const int c4 = t & 31;
#pragma unroll
    for (int p = 0; p < 8; ++p) {
        const int n = p * 8 + nl;
        const float4 v = reinterpret_cast<const float4*>(Y + (size_t)(n0 + n) * C_DIM)[c4];
        reinterpret_cast<float4*>(Yl[n])[c4] = v;
        float sq = v.x * v.x + v.y * v.y + v.z * v.z + v.w * v.w;
#pragma unroll
        for (int m = 16; m >= 1; m >>= 1) sq += __shfl_xor(sq, m, 64);
        if (c4 == 0) ysql[n] = sq;
    }
    __syncthreads();
    unsigned* YtU = (unsigned*)Yt;              // row stride N/2 dwords
    const int nd0 = n0 >> 1;
    const int n2  = t & 31;
    const int rr  = t >> 5;
#pragma unroll
    for (int p = 0; p < 16; ++p) {
        const int c = p * 8 + rr;
        YtU[(size_t)c * (N_PTS / 2) + nd0 + n2] = pack_h2(Yl[2 * n2][c], Yl[2 * n2 + 1][c]);
    }
    if (t < 32) {
        YtU[(size_t)128 * (N_PTS / 2) + nd0 + t] = pack_h2(ysql[2 * t], ysql[2 * t + 1]);
    } else if (t < 64) {
        YtU[(size_t)129 * (N_PTS / 2) + nd0 + (t - 32)] = 0x3C003C00u;  // (1.0h, 1.0h)
    }
    for (int idx = t; idx < 14 * 32; idx += 256) {
        YtU[(size_t)(130 + (idx >> 5)) * (N_PTS / 2) + nd0 + (idx & 31)] = 0u;
    }
}

// ---------------------------------------------------------------------------
// K1: split-K MFMA GEMM, NO LDS, NO BARRIERS. Waves free-run.
//   wpart[ch][fk][c] = sum_{n in chunk} M[n][fk] * Yt[c][n]
// Block 256 thr = 4 waves; block owns 128 fk (wave w: fk = fk0+w*32, 2
// m-tiles of 16); 9 c-tiles of 16 cover 144 padded c-rows. Per 32-n k-step:
// A-frags gathered from global M (8 scalar dword loads per m-tile: 16 lanes
// x 64B segments, 4 quad-rows -> full cachelines in L1/L2; M is L3-resident),
// B-frags 16B/lane from Yt (L2-resident, shared by all 4 waves via L1).
// ---------------------------------------------------------------------------
__global__ __launch_bounds__(256) void gemm_k(const float* __restrict__ M,
                                              const _Float16* __restrict__ Yt,
                                              float* __restrict__ wpart,
                                              int cn) {
    const int t    = threadIdx.x;
    const int fk0  = blockIdx.x * 128;
    const int ch   = blockIdx.y;
    const int n0   = ch * cn;
    const int w    = t >> 6;
    const int l    = t & 63;
    const int quad = l >> 4;
    const int cl   = l & 15;
    const int fkA  = fk0 + w * 32 + cl;     // A m-row for mt=0 (mt=1 -> +16)

    f32x4 acc[2][9] = {};

    for (int nb = 0; nb < cn; nb += 32) {
        const int nbase = n0 + nb + quad * 8;
        f16x8 b[9];
#pragma unroll
        for (int ct = 0; ct < 9; ++ct)
            b[ct] = *reinterpret_cast<const f16x8*>(
                Yt + (size_t)(ct * 16 + cl) * N_PTS + nbase);
        f16x8 a0, a1;
#pragma unroll
        for (int j = 0; j < 8; ++j) {
            const float* row = M + (size_t)(nbase + j) * FK;
            a0[j] = (_Float16)row[fkA];
            a1[j] = (_Float16)row[fkA + 16];
        }
#pragma unroll
        for (int ct = 0; ct < 9; ++ct) {
            acc[0][ct] = __builtin_amdgcn_mfma_f32_16x16x32_f16(a0, b[ct], acc[0][ct], 0, 0, 0);
            acc[1][ct] = __builtin_amdgcn_mfma_f32_16x16x32_f16(a1, b[ct], acc[1][ct], 0, 0, 0);
        }
    }

    // D layout: col(c) = lane&15, row(fk) = quad*4 + reg
    float* wp = wpart + (size_t)ch * FK * CW;
#pragma unroll
    for (int mt = 0; mt < 2; ++mt) {
#pragma unroll
        for (int ct = 0; ct < 9; ++ct) {
            const int c = ct * 16 + cl;
            if (c < CW) {
#pragma unroll
                for (int r = 0; r < 4; ++r) {
                    const int fk = fk0 + w * 32 + mt * 16 + quad * 4 + r;
                    wp[(size_t)fk * CW + c] = acc[mt][ct][r];
                }
            }
        }
    }
}

// ---------------------------------------------------------------------------
// R1: chunk reduction wpart -> W. 528 blocks x 128 thr, 4-way ILP over chunks.
// ---------------------------------------------------------------------------
__global__ __launch_bounds__(128) void reduce_w_k(const float* __restrict__ wpart,
                                                  float* __restrict__ W, int nchunk) {
    const int idx = blockIdx.x * 128 + threadIdx.x;   // float4 index, grid exact
    const float4* src = reinterpret_cast<const float4*>(wpart);
    const size_t cs = (size_t)FK * CW / 4;
    float4 s0 = make_float4(0.f, 0.f, 0.f, 0.f), s1 = s0, s2 = s0, s3 = s0;
    int ch = 0;
    for (; ch + 3 < nchunk; ch += 4) {
        const float4 a = src[idx + (size_t)(ch + 0) * cs];
        const float4 b = src[idx + (size_t)(ch + 1) * cs];
        const float4 c = src[idx + (size_t)(ch + 2) * cs];
        const float4 d = src[idx + (size_t)(ch + 3) * cs];
        s0.x += a.x; s0.y += a.y; s0.z += a.z; s0.w += a.w;
        s1.x += b.x; s1.y += b.y; s1.z += b.z; s1.w += b.w;
        s2.x += c.x; s2.y += c.y; s2.z += c.z; s2.w += c.w;
        s3.x += d.x; s3.y += d.y; s3.z += d.z; s3.w += d.w;
    }
    for (; ch < nchunk; ++ch) {
        const float4 a = src[idx + (size_t)ch * cs];
        s0.x += a.x; s0.y += a.y; s0.z += a.z; s0.w += a.w;
    }
    float4 r;
    r.x = (s0.x + s1.x) + (s2.x + s3.x);
    r.y = (s0.y + s1.y) + (s2.y + s3.y);
    r.z = (s0.z + s1.z) + (s2.z + s3.z);
    r.w = (s0.w + s1.w) + (s2.w + s3.w);
    reinterpret_cast<float4*>(W)[idx] = r;
}

// ---------------------------------------------------------------------------
// R2: per-feature epilogue on reduced W. wv = (S1 - c_sq*(B'+EPS))/B' (exact
// identity), entropy, neighbor repulsion, strict-upper Gram for inter.
// ---------------------------------------------------------------------------
__global__ __launch_bounds__(256) void epilogue_k(const float* __restrict__ W,
                                                  float* __restrict__ fpart) {
    __shared__ __align__(16) float Wl[32][CW];
    __shared__ float Bv[32], Binv[32], S1v[32], csq[32];
    __shared__ float scr[32][8];
    __shared__ float4 red4[256];
    const int t = threadIdx.x;
    const int f = blockIdx.x;

    for (int e = t; e < 32 * 33; e += 256) {
        const int k = e / 33, c4 = e % 33;
        reinterpret_cast<float4*>(Wl[k])[c4] =
            reinterpret_cast<const float4*>(W + (size_t)(f * 32 + k) * CW)[c4];
    }
    __syncthreads();
    if (t < 32) {
        const float B = Wl[t][129] + EPS_F;
        Bv[t] = B; Binv[t] = 1.0f / B; S1v[t] = Wl[t][128];
    }
    __syncthreads();
    {   // centroids in place + c_sq partials
        const int k = t >> 3, g = t & 7;
        const float ib = Binv[k];
        float s = 0.f;
        for (int c = g * 16; c < g * 16 + 16; ++c) {
            const float v = Wl[k][c] * ib;
            Wl[k][c] = v;
            s = fmaf(v, v, s);
        }
        scr[k][g] = s;
    }
    __syncthreads();
    if (t < 32) {
        float s = 0.f;
#pragma unroll
        for (int g = 0; g < 8; ++g) s += scr[t][g];
        csq[t] = s;
    }
    __syncthreads();

    float my_disp = 0.f, my_ent = 0.f, my_rep = 0.f, my_inter = 0.f;
    if (t < 32) {
        my_disp = (S1v[t] - csq[t] * (Bv[t] + EPS_F)) * Binv[t];
        const float p = Bv[t] * (1.0f / (float)N_PTS);
        my_ent = p * logf(p + EPS_F);
    }
    {   // neighbor repulsion
        const int pr = t >> 3, g = t & 7;
        float s = 0.f;
        if (pr < 31) {
            for (int c = g * 16; c < g * 16 + 16; ++c) {
                const float d = Wl[pr][c] - Wl[pr + 1][c];
                s = fmaf(d, d, s);
            }
        }
        __syncthreads();
        scr[pr][g] = s;
    }
    __syncthreads();
    if (t < 31) {
        float d = 0.f;
#pragma unroll
        for (int g = 0; g < 8; ++g) d += scr[t][g];
        my_rep = expf(-d);
    }
    // all-pairs inter (strict upper), float4 dots
#pragma unroll
    for (int s4 = 0; s4 < 4; ++s4) {
        const int slot = t + s4 * 256;
        const int k = slot >> 5, j = slot & 31;
        if (k < j) {
            float dot = 0.f;
            for (int c4 = 0; c4 < 32; ++c4) {
                const float4 a = reinterpret_cast<const float4*>(Wl[k])[c4];
                const float4 b = reinterpret_cast<const float4*>(Wl[j])[c4];
                dot = fmaf(a.x, b.x, dot); dot = fmaf(a.y, b.y, dot);
                dot = fmaf(a.z, b.z, dot); dot = fmaf(a.w, b.w, dot);
            }
            my_inter += expf(-(csq[k] + csq[j] - 2.0f * dot));
        }
    }
    red4[t] = make_float4(my_disp, my_ent, my_rep, my_inter);
    __syncthreads();
    for (int off = 128; off >= 1; off >>= 1) {
        if (t < off) {
            const float4 a = red4[t], b = red4[t + off];
            red4[t] = make_float4(a.x + b.x, a.y + b.y, a.z + b.z, a.w + b.w);
        }
        __syncthreads();
    }
    if (t == 0) {
        fpart[f * 4 + 0] = red4[0].x;
        fpart[f * 4 + 1] = red4[0].y;
        fpart[f * 4 + 2] = red4[0].z;
        fpart[f * 4 + 3] = red4[0].w;
    }
}

// ---------------------------------------------------------------------------
// K3: reduce 64 per-feature partials -> 5 scalar outputs
// ---------------------------------------------------------------------------
__global__ void final_reduce_k(const float* __restrict__ fpart,
                               float* __restrict__ out) {
    const int t = threadIdx.x;  // 64 threads
    float4 v = reinterpret_cast<const float4*>(fpart)[t];
#pragma unroll
    for (int m = 32; m >= 1; m >>= 1) {
        v.x += __shfl_xor(v.x, m, 64);
        v.y += __shfl_xor(v.y, m, 64);
        v.z += __shfl_xor(v.z, m, 64);
        v.w += __shfl_xor(v.w, m, 64);
    }
    if (t == 0) {
        const float disp  = v.x, ent = v.y, rep = v.z;
        const float inter = v.w * (1.0f / (float)F_DIM);
        out[0] = disp + 0.1f * ent + 0.5f * rep + 0.3f * inter;
        out[1] = disp;
        out[2] = ent;
        out[3] = rep;
        out[4] = inter;
    }
}

extern "C" void kernel_launch(void* const* d_in, const int* in_sizes, int n_in,
                              void* d_out, int out_size, void* d_ws, size_t ws_size,
                              hipStream_t stream) {
    const float* M = (const float*)d_in[0];   // (16384, 64, 32) fp32
    const float* Y = (const float*)d_in[1];   // (16384, 128) fp32
    float* out = (float*)d_out;               // 5 floats
    char*  ws  = (char*)d_ws;

    const size_t ytBytes = (size_t)CP * N_PTS * sizeof(_Float16);  // 4,718,592
    const size_t wBytes  = (size_t)FK * CW * sizeof(float);        // 1,081,344

    _Float16* Yt    = (_Float16*)ws;
    float*    W     = (float*)(ws + ytBytes);
    float*    fpart = (float*)(ws + ytBytes + wBytes);
    float*    wpart = (float*)(ws + ytBytes + wBytes + 1024);

    const size_t used = ytBytes + wBytes + 1024;
    int nchunk = 32;    // split-K factor -> 16 x 32 = 512 blocks (2/CU)
    while (nchunk > 1 && used + (size_t)nchunk * wBytes > ws_size) nchunk >>= 1;
    const int cn = N_PTS / nchunk;   // multiple of 32

    build_yt_k<<<dim3(N_PTS / 64), dim3(256), 0, stream>>>(Y, Yt);
    gemm_k<<<dim3(16, nchunk), dim3(256), 0, stream>>>(M, Yt, wpart, cn);
    reduce_w_k<<<dim3(FK * CW / 4 / 128), dim3(128), 0, stream>>>(wpart, W, nchunk);
    epilogue_k<<<dim3(F_DIM), dim3(256), 0, stream>>>(W, fpart);
    final_reduce_k<<<dim3(1), dim3(64), 0, stream>>>(fpart, out);
}